// Round 7
// baseline (2373.767 us; speedup 1.0000x reference)
//
#include <hip/hip_runtime.h>
#include <hip/hip_bf16.h>
#include <stdint.h>

#define DECAY 0.951229424500714f
#define TSTEPS 16

// ---- ws layout (bytes) ----
// [0 .. 33.5M)   s0_cl  uchar [t16][b16][pix4096][ic32]   (dead after conv1)
// [0 .. 33.5M)   part   f32   [kc64][nb8][tid256][reg64]  (overlays s0_cl)
// [33.5M..67.1M) flat   bf16  [m256][k65536]
// [67108864..+512K) I   f32   frag-order [nb8][tid256][reg64]
#define OFF_S0CL 0u
#define OFF_PART 0u
#define OFF_FLAT 33554432u
#define OFF_I    67108864u
#define KSPLIT 64
#define KCHUNK (65536 / KSPLIT)   // 1024

typedef __attribute__((ext_vector_type(8))) short short8;
typedef __attribute__((ext_vector_type(4))) float floatx4;

__device__ inline unsigned short f2bf_rne(float f) {
    unsigned u = __float_as_uint(f);
    unsigned r = (u + 0x7FFFu + ((u >> 16) & 1u)) >> 16;
    return (unsigned short)r;
}
__device__ inline float bf2f(unsigned short h) {
    return __uint_as_float(((unsigned)h) << 16);
}

// ---------------- conv0 + LIF0, all t fused; vm0 in regs ----------------
// Bitwise-identical values to the round-2-validated per-t conv0 (same fmaf chain).
__global__ __launch_bounds__(256) void conv0_lif_all(const float* __restrict__ in,
                                                     const float* __restrict__ W0,
                                                     unsigned char* __restrict__ s0g) {
    int tid = threadIdx.x;
    int b = blockIdx.y;
    int p = blockIdx.x * 32 + (tid >> 3);
    int oc0 = (tid & 7) * 4;
    int y = p >> 6, x = p & 63;

    float wreg[4][18];
#pragma unroll
    for (int u = 0; u < 4; ++u)
#pragma unroll
        for (int ic = 0; ic < 2; ++ic)
#pragma unroll
            for (int k = 0; k < 9; ++k)
                wreg[u][ic * 9 + k] = W0[((oc0 + u) * 2 + ic) * 9 + k];

    float vme[4] = {0.f, 0.f, 0.f, 0.f};   // pre-decayed vm state: vm*DECAY*(1-s)
    for (int t = 0; t < TSTEPS; ++t) {
        const float* base = in + (size_t)((b * TSTEPS + t) * 2) * 4096;
        float win[18];
#pragma unroll
        for (int dy = 0; dy < 3; ++dy) {
            int gy = y + dy - 1;
#pragma unroll
            for (int dx = 0; dx < 3; ++dx) {
                int gx = x + dx - 1;
                bool ok = ((unsigned)gy < 64u) && ((unsigned)gx < 64u);
                int k = dy * 3 + dx;
                win[k]     = ok ? base[gy * 64 + gx] : 0.f;         // clip(x,0,1) no-op
                win[9 + k] = ok ? base[4096 + gy * 64 + gx] : 0.f;
            }
        }
        unsigned pk = 0;
#pragma unroll
        for (int u = 0; u < 4; ++u) {
            float I = 0.f;
#pragma unroll
            for (int k = 0; k < 18; ++k) I = fmaf(win[k], wreg[u][k], I);
            float vn = vme[u] + I;
            bool s = vn > 0.5f;
            vme[u] = s ? 0.f : vn * DECAY;
            pk |= (s ? 1u : 0u) << (8 * u);
        }
        *(unsigned*)&s0g[((size_t)((t * 16 + b) * 4096 + p)) * 32 + oc0] = pk;
    }
}

// ---------------- conv1 + LIF1 + maxpool + pack, all t fused (SCALAR fp32) ----------------
// Replicates round-2's per-accumulator fmaf order bit-for-bit:
//   for ic = 0..31 ascending: for tap k = 0..8: acc[u] = fmaf(v[k], W1[oc][ic][k], acc[u])
// (zero halo/padding terms are exact fmaf no-ops). grid (4 ocg, 16 ytile, 16 b), block (64,4).
__global__ __launch_bounds__(256) void conv1_scalar(const unsigned char* __restrict__ s0g,
                                                    const float* __restrict__ W1,
                                                    unsigned short* __restrict__ flatg) {
    __shared__ unsigned char  S_s[6 * 64 * 32];   // rows y0-1..y0+4, [row][x][ic] uchar
    __shared__ unsigned short P_s[4 * 64];        // spike mask (16 oc bits) per [yloc][x]
    int x = threadIdx.x;          // 0..63
    int yloc = threadIdx.y;       // 0..3
    int tid = yloc * 64 + x;
    int ocg = blockIdx.x;         // 0..3
    int ytile = blockIdx.y;       // 0..15
    int b = blockIdx.z;
    int y0 = ytile * 4;

    float vme[16];
#pragma unroll
    for (int u = 0; u < 16; ++u) vme[u] = 0.f;

#pragma unroll 1
    for (int t = 0; t < TSTEPS; ++t) {
        __syncthreads();   // prior iter's S_s reads / P_s reads complete
        // ---- stage 6 rows x 64 x x 32 ic (12288 B, 48 B/thread) ----
        const unsigned char* sb = s0g + (size_t)(t * 16 + b) * 131072;
#pragma unroll
        for (int j = 0; j < 3; ++j) {
            int o = tid * 48 + j * 16;
            int row = o >> 11;            // 2048 B per row
            int rem = o & 2047;
            int gy = y0 - 1 + row;
            uint4 val = make_uint4(0, 0, 0, 0);
            if ((unsigned)gy < 64u)
                val = *(const uint4*)(sb + (size_t)gy * 2048 + rem);
            *(uint4*)&S_s[o] = val;
        }
        __syncthreads();

        float acc[16];
#pragma unroll
        for (int u = 0; u < 16; ++u) acc[u] = 0.f;

#pragma unroll
        for (int half = 0; half < 2; ++half) {
            // window: 9 positions x 16 ic (uint4 = 16 uchar)
            uint4 w16[9];
#pragma unroll
            for (int dy = 0; dy < 3; ++dy)
#pragma unroll
                for (int dx = 0; dx < 3; ++dx) {
                    int sx = x + dx - 1;
                    int k = dy * 3 + dx;
                    w16[k] = ((unsigned)sx < 64u)
                        ? *(const uint4*)&S_s[((yloc + dy) * 64 + sx) * 32 + half * 16]
                        : make_uint4(0, 0, 0, 0);
                }
#pragma unroll
            for (int c4 = 0; c4 < 4; ++c4) {
                unsigned cw[9];
#pragma unroll
                for (int k = 0; k < 9; ++k)
                    cw[k] = (c4 == 0) ? w16[k].x : (c4 == 1) ? w16[k].y : (c4 == 2) ? w16[k].z : w16[k].w;
#pragma unroll
                for (int sub = 0; sub < 4; ++sub) {
                    float v[9];
#pragma unroll
                    for (int k = 0; k < 9; ++k) v[k] = (float)((cw[k] >> (8 * sub)) & 0xFFu);
                    int ic = half * 16 + c4 * 4 + sub;   // ascending 0..31
#pragma unroll
                    for (int u = 0; u < 16; ++u) {
                        const float* wp = W1 + ((size_t)(ocg * 16 + u) * 32 + ic) * 9;
#pragma unroll
                        for (int k = 0; k < 9; ++k) acc[u] = fmaf(v[k], wp[k], acc[u]);
                    }
                }
            }
        }

        // ---- LIF1 ----
        unsigned smask = 0;
#pragma unroll
        for (int u = 0; u < 16; ++u) {
            float vn = vme[u] + acc[u];
            bool s = vn > 0.5f;
            vme[u] = s ? 0.f : vn * DECAY;
            smask |= (s ? 1u : 0u) << u;
        }
        P_s[tid] = (unsigned short)smask;
        __syncthreads();

        // ---- 2x2 maxpool + bf16 {0,1} pack: 1024 outputs, 4/thread ----
        size_t fb = (size_t)(t * 16 + b) * 65536;
#pragma unroll
        for (int j = 0; j < 4; ++j) {
            int o = j * 256 + tid;
            int u = o >> 6, py = (o >> 5) & 1, px = o & 31;
            unsigned m = P_s[(py * 2) * 64 + px * 2] | P_s[(py * 2) * 64 + px * 2 + 1]
                       | P_s[(py * 2 + 1) * 64 + px * 2] | P_s[(py * 2 + 1) * 64 + px * 2 + 1];
            flatg[fb + (size_t)(ocg * 16 + u) * 1024 + (size_t)(ytile * 2 + py) * 32 + px] =
                ((m >> u) & 1u) ? (unsigned short)0x3F80 : (unsigned short)0;
        }
    }
}

// ---------------- dense0: flat[256][65536] @ D0^T, bf16 MFMA hi/lo, frag-linear C ----------------
// Bitwise-identical accumulation to the round-2-validated dense0 (same k-order, same hi/lo).
__global__ __launch_bounds__(256) void dense0_mfma(const float* __restrict__ D0,
                                                   const unsigned short* __restrict__ flat,
                                                   float* __restrict__ part) {
    __shared__ unsigned short A_s[256 * 72];
    __shared__ unsigned short Bh_s[64 * 72];
    __shared__ unsigned short Bl_s[64 * 72];
    int tid = threadIdx.x;
    int nb = blockIdx.x, kc = blockIdx.y;
    int lane = tid & 63, w = tid >> 6, q = lane >> 4, r = lane & 15;
    const size_t kbase = (size_t)kc * KCHUNK;

    floatx4 acc[4][4];
#pragma unroll
    for (int i = 0; i < 4; ++i)
#pragma unroll
        for (int j = 0; j < 4; ++j) acc[i][j] = (floatx4){0.f, 0.f, 0.f, 0.f};

    const unsigned short* aG = flat + (size_t)tid * 65536 + kbase;
    int bn = tid & 63, bks = (tid >> 6) * 8;
    const float* bG = D0 + (size_t)(nb * 64 + bn) * 65536 + kbase + bks;

    for (int k0 = 0; k0 < KCHUNK; k0 += 32) {
        uint4 av[4];
#pragma unroll
        for (int i = 0; i < 4; ++i) av[i] = *(const uint4*)(aG + k0 + i * 8);
        float4 b0 = *(const float4*)(bG + k0);
        float4 b1 = *(const float4*)(bG + k0 + 4);

        __syncthreads();
#pragma unroll
        for (int i = 0; i < 4; ++i) *(uint4*)&A_s[tid * 72 + i * 8] = av[i];

        float f[8] = {b0.x, b0.y, b0.z, b0.w, b1.x, b1.y, b1.z, b1.w};
        unsigned hw[4], lw[4];
#pragma unroll
        for (int j = 0; j < 4; ++j) {
            unsigned short h0 = f2bf_rne(f[2*j]),   h1 = f2bf_rne(f[2*j+1]);
            unsigned short l0 = f2bf_rne(f[2*j]   - bf2f(h0));
            unsigned short l1 = f2bf_rne(f[2*j+1] - bf2f(h1));
            hw[j] = (unsigned)h0 | ((unsigned)h1 << 16);
            lw[j] = (unsigned)l0 | ((unsigned)l1 << 16);
        }
        *(uint4*)&Bh_s[bn * 72 + bks] = make_uint4(hw[0], hw[1], hw[2], hw[3]);
        *(uint4*)&Bl_s[bn * 72 + bks] = make_uint4(lw[0], lw[1], lw[2], lw[3]);
        __syncthreads();

        short8 af[4];
#pragma unroll
        for (int mi = 0; mi < 4; ++mi)
            af[mi] = *(const short8*)&A_s[(w * 64 + mi * 16 + r) * 72 + q * 8];
#pragma unroll
        for (int ni = 0; ni < 4; ++ni) {
            short8 bh = *(const short8*)&Bh_s[(ni * 16 + r) * 72 + q * 8];
            short8 bl = *(const short8*)&Bl_s[(ni * 16 + r) * 72 + q * 8];
#pragma unroll
            for (int mi = 0; mi < 4; ++mi) {
                acc[mi][ni] = __builtin_amdgcn_mfma_f32_16x16x32_bf16(af[mi], bh, acc[mi][ni], 0, 0, 0);
                acc[mi][ni] = __builtin_amdgcn_mfma_f32_16x16x32_bf16(af[mi], bl, acc[mi][ni], 0, 0, 0);
            }
        }
    }

    // fragment-linear C write -> full-line wave stores
    size_t base = (((size_t)(kc * 8 + nb)) * 256 + tid) * 64;
#pragma unroll
    for (int mi = 0; mi < 4; ++mi)
#pragma unroll
        for (int ni = 0; ni < 4; ++ni)
            *(floatx4*)(part + base + (mi * 4 + ni) * 4) = acc[mi][ni];
}

// ---------------- reduce split-K partials (coalesced, frag-order) ----------------
__global__ __launch_bounds__(256) void reduce_part(const float* __restrict__ part,
                                                   float* __restrict__ I) {
    int e = blockIdx.x * 256 + threadIdx.x;
    float s = 0.f;
#pragma unroll 8
    for (int c = 0; c < KSPLIT; ++c) s += part[(size_t)c * 131072 + e];
    I[e] = s;
}

// ---------------- tail: LIF2 + dense1 + LIF3 + acc ----------------
__global__ __launch_bounds__(512) void tail_kernel(const float* __restrict__ D1,
                                                   float* __restrict__ out,
                                                   const float* __restrict__ Ibuf) {
    __shared__ float s2l[16][512];
    __shared__ float d1l[11 * 512];
    __shared__ float pb[2][176];
    int tid = threadIdx.x;
    for (int i = tid; i < 11 * 512; i += 512) d1l[i] = D1[i];

    float vm2[16];
#pragma unroll
    for (int i = 0; i < 16; ++i) vm2[i] = 0.f;
    unsigned s2mask = 0;
    float vm3 = 0.f, s3 = 0.f, accv = 0.f;
    int rb = tid / 11, ro = tid % 11;
    int nb = tid >> 6, ni = (tid >> 4) & 3, rr = tid & 15;
    __syncthreads();

    for (int t = 0; t < TSTEPS; ++t) {
        // phase A: LIF2 — m = t*16+b: w=t>>2, mi=t&3, b = qq*4+rg -> 4 float4 loads
        {
            int w = t >> 2, mi = t & 3;
#pragma unroll
            for (int qq = 0; qq < 4; ++qq) {
                int idx4 = ((nb * 256 + w * 64 + qq * 16 + rr) << 6) + ((mi * 4 + ni) << 2);
                float4 Iv = *(const float4*)&Ibuf[idx4];
                float Ia[4] = {Iv.x, Iv.y, Iv.z, Iv.w};
#pragma unroll
                for (int rg = 0; rg < 4; ++rg) {
                    int b = qq * 4 + rg;
                    float sp = ((s2mask >> b) & 1u) ? 1.f : 0.f;
                    float vm = vm2[b] * DECAY * (1.f - sp) + Ia[rg];
                    vm2[b] = vm;
                    unsigned sb = (vm > 0.5f) ? 1u : 0u;
                    s2mask = (s2mask & ~(1u << b)) | (sb << b);
                    s2l[b][tid] = (float)sb;
                }
            }
        }
        __syncthreads();
        if (tid < 352) {
            int g = tid / 176, r2 = tid % 176;
            int b = r2 / 11, o = r2 % 11;
            float p = 0.f;
            int kb = g * 256;
            for (int k = 0; k < 256; ++k)
                p = fmaf(s2l[b][kb + k], d1l[o * 512 + kb + k], p);
            pb[g][r2] = p;
        }
        __syncthreads();
        if (tid < 176) {
            float I3 = pb[0][tid] + pb[1][tid];
            float vm = vm3 * DECAY * (1.f - s3) + I3;
            vm3 = vm;
            s3 = (vm > 0.5f) ? 1.f : 0.f;
            accv += s3;
        }
        __syncthreads();
    }
    if (tid < 176) out[rb * 11 + ro] = accv * (1.f / 16.f);
}

extern "C" void kernel_launch(void* const* d_in, const int* in_sizes, int n_in,
                              void* d_out, int out_size, void* d_ws, size_t ws_size,
                              hipStream_t stream) {
    (void)in_sizes; (void)n_in; (void)out_size; (void)ws_size;
    const float* in = (const float*)d_in[0];
    const float* W0 = (const float*)d_in[1];
    const float* W1 = (const float*)d_in[2];
    const float* D0 = (const float*)d_in[3];
    const float* D1 = (const float*)d_in[4];
    float* out = (float*)d_out;
    char* ws = (char*)d_ws;

    unsigned char*  s0g   = (unsigned char*)(ws + OFF_S0CL);
    unsigned short* flatg = (unsigned short*)(ws + OFF_FLAT);
    float*          partg = (float*)(ws + OFF_PART);
    float*          Ig    = (float*)(ws + OFF_I);

    conv0_lif_all<<<dim3(128, 16), 256, 0, stream>>>(in, W0, s0g);
    conv1_scalar<<<dim3(4, 16, 16), dim3(64, 4), 0, stream>>>(s0g, W1, flatg);
    dense0_mfma<<<dim3(8, KSPLIT), 256, 0, stream>>>(D0, flatg, partg);
    reduce_part<<<512, 256, 0, stream>>>(partg, Ig);
    tail_kernel<<<1, 512, 0, stream>>>(D1, out, Ig);
}